// Round 2
// baseline (5989.079 us; speedup 1.0000x reference)
//
#include <hip/hip_runtime.h>
#include <hip/hip_bf16.h>

#define NN 20000
#define TT 60
#define DD 20
#define HH 128
#define KK 148   // DD + HH
#define EE 320000
#define EA 340000  // EE + NN (self loops)

typedef unsigned short u16;
typedef unsigned int u32;

__device__ __forceinline__ float bf2f(u16 u){ return __uint_as_float(((u32)u)<<16); }
__device__ __forceinline__ float sigf(float x){ return 1.f/(1.f+__expf(-x)); }
__device__ __forceinline__ float tanhf_fast(float x){
  float e = __expf(2.f*x);
  return 1.f - 2.f/(e+1.f);   // saturates to +-1, no NaN
}
// dtype-flexible input load: isbf ? bf16[i] : float[i]
__device__ __forceinline__ float ldin(const void* p, size_t i, int isbf){
  return isbf ? bf2f(((const u16*)p)[i]) : ((const float*)p)[i];
}

// ---------------- dtype probe: even-index u16s of fp32 data are mantissa junk ----------
__global__ void detect_kernel(const u16* __restrict__ x, int* __restrict__ flag){
  __shared__ int cnt;
  if (threadIdx.x == 0) cnt = 0;
  __syncthreads();
  // x_win ~ N(0,1): as bf16 stream, even u16s ARE elements -> |v| in [1e-6,1e3] a.s.
  // as fp32 stream, even u16s are low mantissa halves -> uniform exponent, ~12% in range
  float v = bf2f(x[(size_t)threadIdx.x * 2]);
  float a = fabsf(v);
  int ok = (a > 1e-6f && a < 1e3f) ? 1 : 0;   // NaN -> 0
  atomicAdd(&cnt, ok);
  __syncthreads();
  if (threadIdx.x == 0) *flag = (cnt > 400) ? 1 : 0;
}

// ---------------- weight prep: fuse [Wih | Whh] -> Wt[148][512] fp32, bias = bih+bhh ----
__global__ void prep_kernel(const void* __restrict__ Wih, const void* __restrict__ Whh,
                            const void* __restrict__ bih, const void* __restrict__ bhh,
                            const int* __restrict__ flag,
                            float* __restrict__ Wt, float* __restrict__ bias){
  int isbf = *flag;
  int idx = blockIdx.x*256 + threadIdx.x;
  if (idx < KK*512){
    int k = idx >> 9, g = idx & 511;
    Wt[idx] = (k < DD) ? ldin(Wih, (size_t)g*DD + k, isbf)
                       : ldin(Whh, (size_t)g*HH + (k-DD), isbf);
  }
  if (idx < 512) bias[idx] = ldin(bih, idx, isbf) + ldin(bhh, idx, isbf);
}

// ---------------- LSTM: 32 nodes/block, 60 steps, gates[32,512] = z[32,148] @ Wt -------
__global__ __launch_bounds__(256) void lstm_kernel(const void* __restrict__ xwin,
    const float* __restrict__ Wt, const float* __restrict__ bias,
    const int* __restrict__ flag, float* __restrict__ node_h){
  __shared__ float z[32][152];          // [node][ x(0..19) | h(20..147) ], pad 152
  const int isbf = *flag;
  const int tid = threadIdx.x;
  const int nb  = blockIdx.x * 32;
  const int j   = tid & 63;             // channel-pair group
  const int ng  = tid >> 6;             // node group (wave id)
  const int ch0 = j*2;
  const int n0  = ng*8;

  float bI0=bias[ch0],     bI1=bias[ch0+1];
  float bF0=bias[128+ch0], bF1=bias[128+ch0+1];
  float bG0=bias[256+ch0], bG1=bias[256+ch0+1];
  float bO0=bias[384+ch0], bO1=bias[384+ch0+1];

  float cst[8][2];
  #pragma unroll
  for (int i=0;i<8;i++){
    cst[i][0]=0.f; cst[i][1]=0.f;
    z[n0+i][DD+ch0]=0.f; z[n0+i][DD+ch0+1]=0.f;
  }

  #pragma unroll 1
  for (int t=0;t<TT;t++){
    __syncthreads();                     // x slots free to overwrite
    for (int idx=tid; idx<32*DD; idx+=256){
      int node = idx/DD, el = idx - node*DD;
      z[node][el] = ldin(xwin, (size_t)(nb+node)*(TT*DD) + t*DD + el, isbf);
    }
    __syncthreads();

    float acc[4][8][2];
    #pragma unroll
    for (int q=0;q<4;q++)
      #pragma unroll
      for (int i=0;i<8;i++){ acc[q][i][0]=0.f; acc[q][i][1]=0.f; }

    const float* wp = Wt + ch0;
    #pragma unroll 2
    for (int k=0;k<KK;k++){
      float zv[8];
      #pragma unroll
      for (int i=0;i<8;i++) zv[i] = z[n0+i][k];   // LDS broadcast (wave-uniform)
      #pragma unroll
      for (int q=0;q<4;q++){
        float2 w = *(const float2*)(wp + k*512 + q*128);  // coalesced across lanes
        #pragma unroll
        for (int i=0;i<8;i++){
          acc[q][i][0] = fmaf(w.x, zv[i], acc[q][i][0]);
          acc[q][i][1] = fmaf(w.y, zv[i], acc[q][i][1]);
        }
      }
    }
    __syncthreads();                     // all z reads done before h overwrite

    #pragma unroll
    for (int i=0;i<8;i++){
      #pragma unroll
      for (int c=0;c<2;c++){
        float gi = acc[0][i][c] + (c? bI1:bI0);
        float gf = acc[1][i][c] + (c? bF1:bF0);
        float gg = acc[2][i][c] + (c? bG1:bG0);
        float go = acc[3][i][c] + (c? bO1:bO0);
        float cc = sigf(gf)*cst[i][c] + sigf(gi)*tanhf_fast(gg);
        cst[i][c] = cc;
        z[n0+i][DD+ch0+c] = sigf(go)*tanhf_fast(cc);
      }
    }
  }
  __syncthreads();
  #pragma unroll
  for (int i=0;i<8;i++){
    float2 v; v.x = z[n0+i][DD+ch0]; v.y = z[n0+i][DD+ch0+1];
    *(float2*)(node_h + (size_t)(nb+n0+i)*HH + ch0) = v;
  }
}

// ---------------- Y[M,128] = X[M,128] @ W[128,128] (W external dtype) ------------------
__global__ __launch_bounds__(256) void gemm_kernel(const float* __restrict__ X,
    const void* __restrict__ W, const int* __restrict__ flag, float* __restrict__ Y){
  __shared__ float xs[32][128];
  const int isbf = *flag;
  const int tid = threadIdx.x;
  const int rb  = blockIdx.x*32;
  for (int idx=tid; idx<1024; idx+=256){
    int row = idx>>5, k4 = (idx&31)*4;
    *(float4*)&xs[row][k4] = *(const float4*)(X + (size_t)(rb+row)*128 + k4);
  }
  __syncthreads();
  const int col = tid & 127;
  const int r0  = (tid>>7)*16;
  float acc[16];
  #pragma unroll
  for (int r=0;r<16;r++) acc[r]=0.f;
  for (int k=0;k<128;k++){
    float w = ldin(W, (size_t)k*128 + col, isbf);
    #pragma unroll
    for (int r=0;r<16;r++) acc[r] = fmaf(w, xs[r0+r][k], acc[r]);
  }
  #pragma unroll
  for (int r=0;r<16;r++) Y[(size_t)(rb+r0+r)*128 + col] = acc[r];
}

// ---------------- per-node attention logits asr/adt [N,4] ------------------------------
__global__ __launch_bounds__(256) void att_kernel(const float* __restrict__ XH,
    const void* __restrict__ att_s, const void* __restrict__ att_d,
    const int* __restrict__ flag, float* __restrict__ asr, float* __restrict__ adt){
  __shared__ float as_[128], ad_[128];
  int isbf = *flag;
  int tid = threadIdx.x;
  if (tid < 128){ as_[tid] = ldin(att_s, tid, isbf); ad_[tid] = ldin(att_d, tid, isbf); }
  __syncthreads();
  int n = blockIdx.x*64 + (tid>>2);
  int h = tid & 3;
  if (n >= NN) return;
  const float* row = XH + (size_t)n*128 + h*32;
  float s=0.f, d=0.f;
  #pragma unroll
  for (int c=0;c<32;c++){
    float v = row[c];
    s = fmaf(v, as_[h*32+c], s);
    d = fmaf(v, ad_[h*32+c], d);
  }
  asr[n*4+h]=s; adt[n*4+h]=d;
}

// ---------------- edge softmax (3 passes, atomics) --------------------------------------
__device__ __forceinline__ u32 fkey(float x){
  u32 b = __float_as_uint(x);
  return (b & 0x80000000u) ? ~b : (b | 0x80000000u);
}
__device__ __forceinline__ float unkey(u32 k){
  return (k & 0x80000000u) ? __uint_as_float(k ^ 0x80000000u) : __uint_as_float(~k);
}
__device__ __forceinline__ void edge_sd(int e, const int* src, const int* dst, int& s, int& d){
  if (e < EE){ s = src[e]; d = dst[e]; } else { s = e - EE; d = s; }
}

__global__ void edge_max_kernel(const int* __restrict__ src, const int* __restrict__ dst,
    const float* __restrict__ asr, const float* __restrict__ adt, u32* __restrict__ emax){
  int e = blockIdx.x*256 + threadIdx.x;
  if (e >= EA) return;
  int s,d; edge_sd(e, src, dst, s, d);
  float4 a = *(const float4*)(asr + (size_t)s*4);
  float4 b = *(const float4*)(adt + (size_t)d*4);
  float v[4] = {a.x+b.x, a.y+b.y, a.z+b.z, a.w+b.w};
  #pragma unroll
  for (int h=0;h<4;h++){
    float x = v[h] > 0.f ? v[h] : 0.2f*v[h];
    atomicMax(emax + (size_t)d*4 + h, fkey(x));
  }
}

__global__ void edge_exp_kernel(const int* __restrict__ src, const int* __restrict__ dst,
    const float* __restrict__ asr, const float* __restrict__ adt,
    const u32* __restrict__ emax, float* __restrict__ exb, float* __restrict__ den){
  int e = blockIdx.x*256 + threadIdx.x;
  if (e >= EA) return;
  int s,d; edge_sd(e, src, dst, s, d);
  float4 a = *(const float4*)(asr + (size_t)s*4);
  float4 b = *(const float4*)(adt + (size_t)d*4);
  float v[4] = {a.x+b.x, a.y+b.y, a.z+b.z, a.w+b.w};
  uint4 mk = *(const uint4*)(emax + (size_t)d*4);
  u32 mka[4] = {mk.x, mk.y, mk.z, mk.w};
  float4 exv;
  float* exp_ = &exv.x;
  #pragma unroll
  for (int h=0;h<4;h++){
    float x = v[h] > 0.f ? v[h] : 0.2f*v[h];
    float ex = __expf(x - unkey(mka[h]));
    exp_[h] = ex;
    atomicAdd(den + (size_t)d*4 + h, ex);
  }
  *(float4*)(exb + (size_t)e*4) = exv;
}

__global__ __launch_bounds__(256) void edge_agg_kernel(const int* __restrict__ src,
    const int* __restrict__ dst, const float* __restrict__ exb, const float* __restrict__ den,
    const float* __restrict__ XH, float* __restrict__ agg){
  int eg = blockIdx.x*2 + (threadIdx.x>>7);
  int c  = threadIdx.x & 127;
  if (eg >= EA) return;
  int s,d; edge_sd(eg, src, dst, s, d);
  int h = c>>5;
  float w = exb[(size_t)eg*4 + h] / (den[(size_t)d*4 + h] + 1e-16f);
  atomicAdd(agg + (size_t)d*128 + c, w * XH[(size_t)s*128 + c]);
}

// ---------------- epilogues -------------------------------------------------------------
__global__ void elu_kernel(float* __restrict__ buf, const void* __restrict__ bias,
                           const int* __restrict__ flag){
  int isbf = *flag;
  int idx = blockIdx.x*256 + threadIdx.x;
  if (idx >= NN*128) return;
  float v = buf[idx] + ldin(bias, idx & 127, isbf);
  buf[idx] = v > 0.f ? v : expm1f(v);
}

__global__ void head_kernel(const float* __restrict__ Hf, const void* __restrict__ Wh,
    const void* __restrict__ bh, const int* __restrict__ flag, void* __restrict__ out){
  int isbf = *flag;
  int n = blockIdx.x*256 + threadIdx.x;
  if (n >= NN) return;
  float a0 = ldin(bh, 0, isbf), a1 = ldin(bh, 1, isbf);
  const float* row = Hf + (size_t)n*128;
  #pragma unroll 4
  for (int k=0;k<128;k++){
    float v = row[k];
    a0 = fmaf(v, ldin(Wh, (size_t)k*2,   isbf), a0);
    a1 = fmaf(v, ldin(Wh, (size_t)k*2+1, isbf), a1);
  }
  if (isbf){
    __hip_bfloat16 h0 = __float2bfloat16(a0);
    __hip_bfloat16 h1 = __float2bfloat16(a1);
    u16* o = (u16*)out;
    o[n*2]   = *(u16*)&h0;
    o[n*2+1] = *(u16*)&h1;
  } else {
    float* o = (float*)out;
    o[n*2]   = a0;
    o[n*2+1] = a1;
  }
}

// ---------------- launch ----------------------------------------------------------------
extern "C" void kernel_launch(void* const* d_in, const int* in_sizes, int n_in,
                              void* d_out, int out_size, void* d_ws, size_t ws_size,
                              hipStream_t stream){
  const void* xwin = d_in[0];
  const int* eidx  = (const int*)d_in[1];
  const void* Wih  = d_in[2];
  const void* Whh  = d_in[3];
  const void* bih  = d_in[4];
  const void* bhh  = d_in[5];
  const void* W1   = d_in[6];
  const void* as1  = d_in[7];
  const void* ad1  = d_in[8];
  const void* b1   = d_in[9];
  const void* W2   = d_in[10];
  const void* as2  = d_in[11];
  const void* ad2  = d_in[12];
  const void* b2   = d_in[13];
  const void* Wh   = d_in[14];
  const void* bh   = d_in[15];
  const int* src = eidx;
  const int* dst = eidx + EE;

  char* ws = (char*)d_ws;
  size_t off = 0;
  auto alloc = [&](size_t bytes)->void*{
    void* p = ws + off; off += (bytes + 255) & ~(size_t)255; return p;
  };
  float* Wt   = (float*)alloc((size_t)KK*512*sizeof(float));
  float* bias = (float*)alloc(512*sizeof(float));
  float* bufA = (float*)alloc((size_t)NN*128*sizeof(float));  // node_h -> agg2/h2
  float* bufB = (float*)alloc((size_t)NN*128*sizeof(float));  // xh1 -> xh2
  float* bufC = (float*)alloc((size_t)NN*128*sizeof(float));  // agg1/h1
  float* asr  = (float*)alloc((size_t)NN*4*sizeof(float));
  float* adt  = (float*)alloc((size_t)NN*4*sizeof(float));
  u32*   emax = (u32*)  alloc((size_t)NN*4*sizeof(u32));
  float* den  = (float*)alloc((size_t)NN*4*sizeof(float));
  float* exb  = (float*)alloc((size_t)EA*4*sizeof(float));
  int*   flag = (int*)  alloc(sizeof(int));
  (void)ws_size; (void)in_sizes; (void)n_in; (void)out_size;

  detect_kernel<<<1, 256, 0, stream>>>((const u16*)xwin, flag);
  prep_kernel<<<(KK*512+255)/256, 256, 0, stream>>>(Wih, Whh, bih, bhh, flag, Wt, bias);
  lstm_kernel<<<NN/32, 256, 0, stream>>>(xwin, Wt, bias, flag, bufA);

  const int EGRID = (EA+255)/256;
  // ---- GAT layer 1 ----
  gemm_kernel<<<NN/32, 256, 0, stream>>>(bufA, W1, flag, bufB);
  att_kernel<<<(NN+63)/64, 256, 0, stream>>>(bufB, as1, ad1, flag, asr, adt);
  hipMemsetAsync(emax, 0, (size_t)NN*4*sizeof(u32), stream);
  hipMemsetAsync(den,  0, (size_t)NN*4*sizeof(float), stream);
  edge_max_kernel<<<EGRID, 256, 0, stream>>>(src, dst, asr, adt, emax);
  edge_exp_kernel<<<EGRID, 256, 0, stream>>>(src, dst, asr, adt, emax, exb, den);
  hipMemsetAsync(bufC, 0, (size_t)NN*128*sizeof(float), stream);
  edge_agg_kernel<<<EA/2, 256, 0, stream>>>(src, dst, exb, den, bufB, bufC);
  elu_kernel<<<(NN*128+255)/256, 256, 0, stream>>>(bufC, b1, flag);
  // ---- GAT layer 2 ----
  gemm_kernel<<<NN/32, 256, 0, stream>>>(bufC, W2, flag, bufB);
  att_kernel<<<(NN+63)/64, 256, 0, stream>>>(bufB, as2, ad2, flag, asr, adt);
  hipMemsetAsync(emax, 0, (size_t)NN*4*sizeof(u32), stream);
  hipMemsetAsync(den,  0, (size_t)NN*4*sizeof(float), stream);
  edge_max_kernel<<<EGRID, 256, 0, stream>>>(src, dst, asr, adt, emax);
  edge_exp_kernel<<<EGRID, 256, 0, stream>>>(src, dst, asr, adt, emax, exb, den);
  hipMemsetAsync(bufA, 0, (size_t)NN*128*sizeof(float), stream);
  edge_agg_kernel<<<EA/2, 256, 0, stream>>>(src, dst, exb, den, bufB, bufA);
  elu_kernel<<<(NN*128+255)/256, 256, 0, stream>>>(bufA, b2, flag);
  // ---- head ----
  head_kernel<<<(NN+255)/256, 256, 0, stream>>>(bufA, Wh, bh, flag, d_out);
}

// Round 3
// 1638.764 us; speedup vs baseline: 3.6546x; 3.6546x over previous
//
#include <hip/hip_runtime.h>
#include <hip/hip_bf16.h>

#define NN 20000
#define TT 60
#define DD 20
#define HH 128
#define KK 148      // DD + HH
#define KP 160      // K padded to 5 k-tiles of 32
#define EE 320000
#define EA 340000   // EE + NN (self loops)
#define ZSTRIDE 168 // z row stride in u16 (21*8 -> b128 conflict-free, 16B aligned)

typedef unsigned short u16;
typedef unsigned int u32;
typedef __attribute__((ext_vector_type(8))) short bf16x8;  // 8 bf16 = 4 VGPRs
typedef __attribute__((ext_vector_type(4))) float f32x4;

__device__ __forceinline__ float bf2f(u16 u){ return __uint_as_float(((u32)u)<<16); }
__device__ __forceinline__ u16 f2bf(float f){
  __hip_bfloat16 b = __float2bfloat16(f);
  return *(u16*)&b;
}
__device__ __forceinline__ float sigf(float x){ return 1.f/(1.f+__expf(-x)); }
__device__ __forceinline__ float tanhf_fast(float x){
  float e = __expf(2.f*x);
  return 1.f - 2.f/(e+1.f);   // saturates to +-1, no NaN
}
// dtype-flexible input load: isbf ? bf16[i] : float[i]
__device__ __forceinline__ float ldin(const void* p, size_t i, int isbf){
  return isbf ? bf2f(((const u16*)p)[i]) : ((const float*)p)[i];
}

// ---------------- dtype probe: even-index u16s of fp32 data are mantissa junk ----------
__global__ void detect_kernel(const u16* __restrict__ x, int* __restrict__ flag){
  __shared__ int cnt;
  if (threadIdx.x == 0) cnt = 0;
  __syncthreads();
  float v = bf2f(x[(size_t)threadIdx.x * 2]);
  float a = fabsf(v);
  int ok = (a > 1e-6f && a < 1e3f) ? 1 : 0;   // NaN -> 0
  atomicAdd(&cnt, ok);
  __syncthreads();
  if (threadIdx.x == 0) *flag = (cnt > 400) ? 1 : 0;
}

// ---------------- prep: Wfrag = fused [Wih|Whh] in MFMA B-fragment layout; bias --------
// Layout: Wfrag[((w*40 + ct*5 + kt)*64 + lane)*8 + j], value = Wt[k][col] bf16
//   col = q*128 + w*32 + hh*16 + (lane&15), q=ct>>1, hh=ct&1
//   k   = kt*32 + (lane>>4)*8 + j;  Wt[k][g] = k<20 ? Wih[g][k] : k<148 ? Whh[g][k-20] : 0
__global__ void prep_kernel(const void* __restrict__ Wih, const void* __restrict__ Whh,
                            const void* __restrict__ bih, const void* __restrict__ bhh,
                            const int* __restrict__ flag,
                            u16* __restrict__ Wfrag, float* __restrict__ bias){
  int isbf = *flag;
  int idx = blockIdx.x*256 + threadIdx.x;
  if (idx < 4*40*64*8){
    int j  = idx & 7;
    int l  = (idx >> 3) & 63;
    int f  = (idx >> 9) % 40;
    int w  = idx / (40*64*8);
    int kt = f % 5, ct = f / 5, q = ct >> 1, hh = ct & 1;
    int col = q*128 + w*32 + hh*16 + (l & 15);
    int k   = kt*32 + (l >> 4)*8 + j;
    float v = 0.f;
    if (k < DD)       v = ldin(Wih, (size_t)col*DD + k, isbf);
    else if (k < KK)  v = ldin(Whh, (size_t)col*HH + (k - DD), isbf);
    Wfrag[idx] = f2bf(v);
  }
  if (idx < 512) bias[idx] = ldin(bih, idx, isbf) + ldin(bhh, idx, isbf);
}

// ---------------- LSTM: MFMA recurrence, weights resident in registers ------------------
// 32 nodes/block, 256 threads (4 waves). Wave w owns channels [32w,32w+32) for all 4
// gates -> c/h update is wave-local. B-frags (40 per wave) loaded once before t-loop.
__global__ __launch_bounds__(256, 1) void lstm_kernel(const void* __restrict__ xwin,
    const u16* __restrict__ Wfrag, const float* __restrict__ bias,
    const int* __restrict__ flag, float* __restrict__ node_h){
  __shared__ u16 z[32*ZSTRIDE];   // [node][ x(0..19) | h(20..147) | pad ] bf16
  const int isbf = *flag;
  const int tid  = threadIdx.x;
  const int lane = tid & 63;
  const int w    = tid >> 6;
  const int nb   = blockIdx.x * 32;
  const int l15  = lane & 15;
  const int quad = lane >> 4;

  // ---- B fragments: 40 x bf16x8 = 160 VGPRs, persistent across all 60 steps ----
  bf16x8 B[40];
  {
    const bf16x8* bp = (const bf16x8*)Wfrag;
    #pragma unroll
    for (int f = 0; f < 40; f++) B[f] = bp[(size_t)(w*40 + f)*64 + lane];
  }

  // ---- per-lane gate biases (ch = w*32 + hh*16 + l15) ----
  float bg[4][2];
  #pragma unroll
  for (int q = 0; q < 4; q++)
    #pragma unroll
    for (int hh = 0; hh < 2; hh++)
      bg[q][hh] = bias[q*128 + w*32 + hh*16 + l15];

  // ---- zero z (h cols + pad), then fill x_0 ----
  for (int i = tid; i < 32*(ZSTRIDE/2); i += 256) ((u32*)z)[i] = 0;

  // x loader: element idx in [0,640): node=idx/20, el=idx%20 (fixed per thread)
  int x0n, x0e, x1n, x1e, x2n, x2e, has3;
  { int i0 = tid, i1 = tid + 256, i2 = tid + 512;
    x0n = i0/20; x0e = i0 - x0n*20;
    x1n = i1/20; x1e = i1 - x1n*20;
    x2n = i2/20; x2e = i2 - x2n*20;
    has3 = (i2 < 640); }

  __syncthreads();   // zero-fill visible before u16 x writes land in same dwords
  {
    const size_t base = (size_t)nb*(TT*DD);
    z[x0n*ZSTRIDE + x0e] = f2bf(ldin(xwin, base + (size_t)x0n*(TT*DD) + x0e, isbf));
    z[x1n*ZSTRIDE + x1e] = f2bf(ldin(xwin, base + (size_t)x1n*(TT*DD) + x1e, isbf));
    if (has3)
      z[x2n*ZSTRIDE + x2e] = f2bf(ldin(xwin, base + (size_t)x2n*(TT*DD) + x2e, isbf));
  }

  f32x4 zf = {0.f, 0.f, 0.f, 0.f};
  f32x4 cst[4];                          // c state tiles [mt*2+hh]
  #pragma unroll
  for (int i = 0; i < 4; i++) cst[i] = zf;

  __syncthreads();

  #pragma unroll 1
  for (int t = 0; t < TT; t++){
    // ---- prefetch x_{t+1} into regs (global, overlaps with A-frag LDS reads) ----
    u16 xp0 = 0, xp1 = 0, xp2 = 0;
    if (t + 1 < TT){
      const size_t base = (size_t)nb*(TT*DD) + (size_t)(t+1)*DD;
      xp0 = f2bf(ldin(xwin, base + (size_t)x0n*(TT*DD) + x0e, isbf));
      xp1 = f2bf(ldin(xwin, base + (size_t)x1n*(TT*DD) + x1e, isbf));
      if (has3) xp2 = f2bf(ldin(xwin, base + (size_t)x2n*(TT*DD) + x2e, isbf));
    }

    // ---- A fragments: lane holds z[mt*16 + l15][kt*32 + quad*8 .. +8] ----
    bf16x8 A[2][5];
    #pragma unroll
    for (int mt = 0; mt < 2; mt++)
      #pragma unroll
      for (int kt = 0; kt < 5; kt++)
        A[mt][kt] = *(const bf16x8*)&z[(mt*16 + l15)*ZSTRIDE + kt*32 + quad*8];

    __syncthreads();   // all z reads done before h/x writes below

    // ---- gates GEMM: 16 independent chains of 5 MFMAs ----
    f32x4 acc[2][4][2];
    #pragma unroll
    for (int mt = 0; mt < 2; mt++)
      #pragma unroll
      for (int q = 0; q < 4; q++)
        #pragma unroll
        for (int hh = 0; hh < 2; hh++){
          const int f0 = (q*2 + hh)*5;
          f32x4 a = __builtin_amdgcn_mfma_f32_16x16x32_bf16(A[mt][0], B[f0+0], zf, 0,0,0);
          a = __builtin_amdgcn_mfma_f32_16x16x32_bf16(A[mt][1], B[f0+1], a, 0,0,0);
          a = __builtin_amdgcn_mfma_f32_16x16x32_bf16(A[mt][2], B[f0+2], a, 0,0,0);
          a = __builtin_amdgcn_mfma_f32_16x16x32_bf16(A[mt][3], B[f0+3], a, 0,0,0);
          a = __builtin_amdgcn_mfma_f32_16x16x32_bf16(A[mt][4], B[f0+4], a, 0,0,0);
          acc[mt][q][hh] = a;
        }

    // ---- gate epilogue: c,h update (wave-local), h -> LDS bf16 ----
    #pragma unroll
    for (int mt = 0; mt < 2; mt++)
      #pragma unroll
      for (int hh = 0; hh < 2; hh++){
        f32x4 cv = cst[mt*2 + hh];
        #pragma unroll
        for (int r = 0; r < 4; r++){
          float gi = acc[mt][0][hh][r] + bg[0][hh];
          float gf = acc[mt][1][hh][r] + bg[1][hh];
          float gg = acc[mt][2][hh][r] + bg[2][hh];
          float go = acc[mt][3][hh][r] + bg[3][hh];
          float cc = sigf(gf)*cv[r] + sigf(gi)*tanhf_fast(gg);
          cv[r] = cc;
          float h = sigf(go)*tanhf_fast(cc);
          const int row = mt*16 + quad*4 + r;
          const int ch  = w*32 + hh*16 + l15;
          z[row*ZSTRIDE + DD + ch] = f2bf(h);
          if (t == TT-1)
            node_h[(size_t)(nb + row)*HH + ch] = h;   // uniform branch, last step only
        }
        cst[mt*2 + hh] = cv;
      }

    // ---- commit x_{t+1} ----
    if (t + 1 < TT){
      z[x0n*ZSTRIDE + x0e] = xp0;
      z[x1n*ZSTRIDE + x1e] = xp1;
      if (has3) z[x2n*ZSTRIDE + x2e] = xp2;
    }
    __syncthreads();
  }
}

// ---------------- Y[M,128] = X[M,128] @ W[128,128] (W external dtype) ------------------
__global__ __launch_bounds__(256) void gemm_kernel(const float* __restrict__ X,
    const void* __restrict__ W, const int* __restrict__ flag, float* __restrict__ Y){
  __shared__ float xs[32][128];
  const int isbf = *flag;
  const int tid = threadIdx.x;
  const int rb  = blockIdx.x*32;
  for (int idx=tid; idx<1024; idx+=256){
    int row = idx>>5, k4 = (idx&31)*4;
    *(float4*)&xs[row][k4] = *(const float4*)(X + (size_t)(rb+row)*128 + k4);
  }
  __syncthreads();
  const int col = tid & 127;
  const int r0  = (tid>>7)*16;
  float acc[16];
  #pragma unroll
  for (int r=0;r<16;r++) acc[r]=0.f;
  for (int k=0;k<128;k++){
    float w = ldin(W, (size_t)k*128 + col, isbf);
    #pragma unroll
    for (int r=0;r<16;r++) acc[r] = fmaf(w, xs[r0+r][k], acc[r]);
  }
  #pragma unroll
  for (int r=0;r<16;r++) Y[(size_t)(rb+r0+r)*128 + col] = acc[r];
}

// ---------------- per-node attention logits asr/adt [N,4] ------------------------------
__global__ __launch_bounds__(256) void att_kernel(const float* __restrict__ XH,
    const void* __restrict__ att_s, const void* __restrict__ att_d,
    const int* __restrict__ flag, float* __restrict__ asr, float* __restrict__ adt){
  __shared__ float as_[128], ad_[128];
  int isbf = *flag;
  int tid = threadIdx.x;
  if (tid < 128){ as_[tid] = ldin(att_s, tid, isbf); ad_[tid] = ldin(att_d, tid, isbf); }
  __syncthreads();
  int n = blockIdx.x*64 + (tid>>2);
  int h = tid & 3;
  if (n >= NN) return;
  const float* row = XH + (size_t)n*128 + h*32;
  float s=0.f, d=0.f;
  #pragma unroll
  for (int c=0;c<32;c++){
    float v = row[c];
    s = fmaf(v, as_[h*32+c], s);
    d = fmaf(v, ad_[h*32+c], d);
  }
  asr[n*4+h]=s; adt[n*4+h]=d;
}

// ---------------- edge softmax (3 passes, atomics) --------------------------------------
__device__ __forceinline__ u32 fkey(float x){
  u32 b = __float_as_uint(x);
  return (b & 0x80000000u) ? ~b : (b | 0x80000000u);
}
__device__ __forceinline__ float unkey(u32 k){
  return (k & 0x80000000u) ? __uint_as_float(k ^ 0x80000000u) : __uint_as_float(~k);
}
__device__ __forceinline__ void edge_sd(int e, const int* src, const int* dst, int& s, int& d){
  if (e < EE){ s = src[e]; d = dst[e]; } else { s = e - EE; d = s; }
}

__global__ void edge_max_kernel(const int* __restrict__ src, const int* __restrict__ dst,
    const float* __restrict__ asr, const float* __restrict__ adt, u32* __restrict__ emax){
  int e = blockIdx.x*256 + threadIdx.x;
  if (e >= EA) return;
  int s,d; edge_sd(e, src, dst, s, d);
  float4 a = *(const float4*)(asr + (size_t)s*4);
  float4 b = *(const float4*)(adt + (size_t)d*4);
  float v[4] = {a.x+b.x, a.y+b.y, a.z+b.z, a.w+b.w};
  #pragma unroll
  for (int h=0;h<4;h++){
    float x = v[h] > 0.f ? v[h] : 0.2f*v[h];
    atomicMax(emax + (size_t)d*4 + h, fkey(x));
  }
}

__global__ void edge_exp_kernel(const int* __restrict__ src, const int* __restrict__ dst,
    const float* __restrict__ asr, const float* __restrict__ adt,
    const u32* __restrict__ emax, float* __restrict__ exb, float* __restrict__ den){
  int e = blockIdx.x*256 + threadIdx.x;
  if (e >= EA) return;
  int s,d; edge_sd(e, src, dst, s, d);
  float4 a = *(const float4*)(asr + (size_t)s*4);
  float4 b = *(const float4*)(adt + (size_t)d*4);
  float v[4] = {a.x+b.x, a.y+b.y, a.z+b.z, a.w+b.w};
  uint4 mk = *(const uint4*)(emax + (size_t)d*4);
  u32 mka[4] = {mk.x, mk.y, mk.z, mk.w};
  float4 exv;
  float* exp_ = &exv.x;
  #pragma unroll
  for (int h=0;h<4;h++){
    float x = v[h] > 0.f ? v[h] : 0.2f*v[h];
    float ex = __expf(x - unkey(mka[h]));
    exp_[h] = ex;
    atomicAdd(den + (size_t)d*4 + h, ex);
  }
  *(float4*)(exb + (size_t)e*4) = exv;
}

__global__ __launch_bounds__(256) void edge_agg_kernel(const int* __restrict__ src,
    const int* __restrict__ dst, const float* __restrict__ exb, const float* __restrict__ den,
    const float* __restrict__ XH, float* __restrict__ agg){
  int eg = blockIdx.x*2 + (threadIdx.x>>7);
  int c  = threadIdx.x & 127;
  if (eg >= EA) return;
  int s,d; edge_sd(eg, src, dst, s, d);
  int h = c>>5;
  float w = exb[(size_t)eg*4 + h] / (den[(size_t)d*4 + h] + 1e-16f);
  atomicAdd(agg + (size_t)d*128 + c, w * XH[(size_t)s*128 + c]);
}

// ---------------- epilogues -------------------------------------------------------------
__global__ void elu_kernel(float* __restrict__ buf, const void* __restrict__ bias,
                           const int* __restrict__ flag){
  int isbf = *flag;
  int idx = blockIdx.x*256 + threadIdx.x;
  if (idx >= NN*128) return;
  float v = buf[idx] + ldin(bias, idx & 127, isbf);
  buf[idx] = v > 0.f ? v : expm1f(v);
}

__global__ void head_kernel(const float* __restrict__ Hf, const void* __restrict__ Wh,
    const void* __restrict__ bh, const int* __restrict__ flag, void* __restrict__ out){
  int isbf = *flag;
  int n = blockIdx.x*256 + threadIdx.x;
  if (n >= NN) return;
  float a0 = ldin(bh, 0, isbf), a1 = ldin(bh, 1, isbf);
  const float* row = Hf + (size_t)n*128;
  #pragma unroll 4
  for (int k=0;k<128;k++){
    float v = row[k];
    a0 = fmaf(v, ldin(Wh, (size_t)k*2,   isbf), a0);
    a1 = fmaf(v, ldin(Wh, (size_t)k*2+1, isbf), a1);
  }
  if (isbf){
    u16* o = (u16*)out;
    o[n*2]   = f2bf(a0);
    o[n*2+1] = f2bf(a1);
  } else {
    float* o = (float*)out;
    o[n*2]   = a0;
    o[n*2+1] = a1;
  }
}

// ---------------- launch ----------------------------------------------------------------
extern "C" void kernel_launch(void* const* d_in, const int* in_sizes, int n_in,
                              void* d_out, int out_size, void* d_ws, size_t ws_size,
                              hipStream_t stream){
  const void* xwin = d_in[0];
  const int* eidx  = (const int*)d_in[1];
  const void* Wih  = d_in[2];
  const void* Whh  = d_in[3];
  const void* bih  = d_in[4];
  const void* bhh  = d_in[5];
  const void* W1   = d_in[6];
  const void* as1  = d_in[7];
  const void* ad1  = d_in[8];
  const void* b1   = d_in[9];
  const void* W2   = d_in[10];
  const void* as2  = d_in[11];
  const void* ad2  = d_in[12];
  const void* b2   = d_in[13];
  const void* Wh   = d_in[14];
  const void* bh   = d_in[15];
  const int* src = eidx;
  const int* dst = eidx + EE;

  char* ws = (char*)d_ws;
  size_t off = 0;
  auto alloc = [&](size_t bytes)->void*{
    void* p = ws + off; off += (bytes + 255) & ~(size_t)255; return p;
  };
  u16*   Wfrag = (u16*) alloc((size_t)4*40*64*8*sizeof(u16));
  float* bias  = (float*)alloc(512*sizeof(float));
  float* bufA  = (float*)alloc((size_t)NN*128*sizeof(float));  // node_h -> agg2/h2
  float* bufB  = (float*)alloc((size_t)NN*128*sizeof(float));  // xh1 -> xh2
  float* bufC  = (float*)alloc((size_t)NN*128*sizeof(float));  // agg1/h1
  float* asr   = (float*)alloc((size_t)NN*4*sizeof(float));
  float* adt   = (float*)alloc((size_t)NN*4*sizeof(float));
  u32*   emax  = (u32*)  alloc((size_t)NN*4*sizeof(u32));
  float* den   = (float*)alloc((size_t)NN*4*sizeof(float));
  float* exb   = (float*)alloc((size_t)EA*4*sizeof(float));
  int*   flag  = (int*)  alloc(sizeof(int));
  (void)ws_size; (void)in_sizes; (void)n_in; (void)out_size;

  detect_kernel<<<1, 256, 0, stream>>>((const u16*)xwin, flag);
  prep_kernel<<<(4*40*64*8+255)/256, 256, 0, stream>>>(Wih, Whh, bih, bhh, flag, Wfrag, bias);
  lstm_kernel<<<NN/32, 256, 0, stream>>>(xwin, Wfrag, bias, flag, bufA);

  const int EGRID = (EA+255)/256;
  // ---- GAT layer 1 ----
  gemm_kernel<<<NN/32, 256, 0, stream>>>(bufA, W1, flag, bufB);
  att_kernel<<<(NN+63)/64, 256, 0, stream>>>(bufB, as1, ad1, flag, asr, adt);
  hipMemsetAsync(emax, 0, (size_t)NN*4*sizeof(u32), stream);
  hipMemsetAsync(den,  0, (size_t)NN*4*sizeof(float), stream);
  edge_max_kernel<<<EGRID, 256, 0, stream>>>(src, dst, asr, adt, emax);
  edge_exp_kernel<<<EGRID, 256, 0, stream>>>(src, dst, asr, adt, emax, exb, den);
  hipMemsetAsync(bufC, 0, (size_t)NN*128*sizeof(float), stream);
  edge_agg_kernel<<<EA/2, 256, 0, stream>>>(src, dst, exb, den, bufB, bufC);
  elu_kernel<<<(NN*128+255)/256, 256, 0, stream>>>(bufC, b1, flag);
  // ---- GAT layer 2 ----
  gemm_kernel<<<NN/32, 256, 0, stream>>>(bufC, W2, flag, bufB);
  att_kernel<<<(NN+63)/64, 256, 0, stream>>>(bufB, as2, ad2, flag, asr, adt);
  hipMemsetAsync(emax, 0, (size_t)NN*4*sizeof(u32), stream);
  hipMemsetAsync(den,  0, (size_t)NN*4*sizeof(float), stream);
  edge_max_kernel<<<EGRID, 256, 0, stream>>>(src, dst, asr, adt, emax);
  edge_exp_kernel<<<EGRID, 256, 0, stream>>>(src, dst, asr, adt, emax, exb, den);
  hipMemsetAsync(bufA, 0, (size_t)NN*128*sizeof(float), stream);
  edge_agg_kernel<<<EA/2, 256, 0, stream>>>(src, dst, exb, den, bufB, bufA);
  elu_kernel<<<(NN*128+255)/256, 256, 0, stream>>>(bufA, b2, flag);
  // ---- head ----
  head_kernel<<<(NN+255)/256, 256, 0, stream>>>(bufA, Wh, bh, flag, d_out);
}

// Round 4
// 1268.031 us; speedup vs baseline: 4.7231x; 1.2924x over previous
//
#include <hip/hip_runtime.h>
#include <hip/hip_bf16.h>

#define NN 20000
#define TT 60
#define DD 20
#define HH 128
#define KK 148      // DD + HH
#define EE 320000
#define EA 340000   // EE + NN (self loops)
#define ZSTRIDE 168 // z row stride in u16 (mult of 8 -> b128-aligned rows)

typedef unsigned short u16;
typedef unsigned int u32;
typedef __attribute__((ext_vector_type(8))) short bf16x8;  // 8 bf16 = 4 VGPRs
typedef __attribute__((ext_vector_type(4))) float f32x4;

__device__ __forceinline__ float bf2f(u16 u){ return __uint_as_float(((u32)u)<<16); }
__device__ __forceinline__ u16 f2bf_fast(float f){   // RNE, no NaN handling (values bounded)
  u32 x = __float_as_uint(f);
  return (u16)((x + 0x7FFFu + ((x >> 16) & 1u)) >> 16);
}
// rcp-based activations: v_exp + v_rcp, no full-precision division sequence
__device__ __forceinline__ float sigf(float x){
  return __builtin_amdgcn_rcpf(1.f + __expf(-x));
}
__device__ __forceinline__ float tanhf_fast(float x){
  return 1.f - 2.f*__builtin_amdgcn_rcpf(1.f + __expf(2.f*x));
}
// dtype-flexible input load: isbf ? bf16[i] : float[i]
__device__ __forceinline__ float ldin(const void* p, size_t i, int isbf){
  return isbf ? bf2f(((const u16*)p)[i]) : ((const float*)p)[i];
}

// ---------------- dtype probe: even-index u16s of fp32 data are mantissa junk ----------
__global__ void detect_kernel(const u16* __restrict__ x, int* __restrict__ flag){
  __shared__ int cnt;
  if (threadIdx.x == 0) cnt = 0;
  __syncthreads();
  float v = bf2f(x[(size_t)threadIdx.x * 2]);
  float a = fabsf(v);
  int ok = (a > 1e-6f && a < 1e3f) ? 1 : 0;   // NaN -> 0
  atomicAdd(&cnt, ok);
  __syncthreads();
  if (threadIdx.x == 0) *flag = (cnt > 400) ? 1 : 0;
}

// ---------------- prep: Wfrag = fused [Wih|Whh] in MFMA B-fragment layout; bias --------
// Consumer: wave w (0..7) owns cols w*16..w*16+15 of each gate q.
// Flat u16 idx = (((w*20 + q*5 + kt)*64 + lane)*8 + j)
//   col = q*128 + w*16 + (lane&15);  k = kt*32 + ((lane>>4)&3)*8 + j
//   Wt[k][g] = k<20 ? Wih[g][k] : k<148 ? Whh[g][k-20] : 0
__global__ void prep_kernel(const void* __restrict__ Wih, const void* __restrict__ Whh,
                            const void* __restrict__ bih, const void* __restrict__ bhh,
                            const int* __restrict__ flag,
                            u16* __restrict__ Wfrag, float* __restrict__ bias){
  int isbf = *flag;
  int idx = blockIdx.x*256 + threadIdx.x;
  if (idx < 8*4*5*64*8){
    int j    = idx & 7;
    int lane = (idx >> 3) & 63;
    int rest = idx >> 9;           // w*20 + q*5 + kt
    int kt = rest % 5, q = (rest/5) & 3, w = rest/20;
    int col = q*128 + w*16 + (lane & 15);
    int k   = kt*32 + ((lane >> 4) & 3)*8 + j;
    float v = 0.f;
    if (k < DD)       v = ldin(Wih, (size_t)col*DD + k, isbf);
    else if (k < KK)  v = ldin(Whh, (size_t)col*HH + (k - DD), isbf);
    Wfrag[idx] = f2bf_fast(v);
  }
  if (idx < 512) bias[idx] = ldin(bih, idx, isbf) + ldin(bhh, idx, isbf);
}

// ---------------- LSTM: MFMA recurrence, 32 nodes/block, 8 waves x 16 channels ---------
// Wave w owns channels [16w,16w+16) for all 4 gates -> c/h update wave-local.
// B-frags (20/wave, 80 VGPR) persist across all 60 steps. Double-buffered z ->
// one barrier per step.
__global__ __launch_bounds__(512, 2) void lstm_kernel(const void* __restrict__ xwin,
    const u16* __restrict__ Wfrag, const float* __restrict__ bias,
    const int* __restrict__ flag, float* __restrict__ node_h){
  __shared__ u16 z[2][32][ZSTRIDE];   // [buf][node][ x(0..19) | h(20..147) | pad0 ]
  const int isbf = *flag;
  const int tid  = threadIdx.x;
  const int lane = tid & 63;
  const int w    = tid >> 6;
  const int nb   = blockIdx.x * 32;
  const int l15  = lane & 15;
  const int quad = lane >> 4;

  // ---- B fragments: 20 x bf16x8 = 80 VGPRs, persistent ----
  bf16x8 B[4][5];
  {
    const bf16x8* bp = (const bf16x8*)Wfrag;
    #pragma unroll
    for (int q = 0; q < 4; q++)
      #pragma unroll
      for (int kt = 0; kt < 5; kt++)
        B[q][kt] = bp[(size_t)((w*20 + q*5 + kt)*64 + lane)];
  }

  float bg[4];
  #pragma unroll
  for (int q = 0; q < 4; q++) bg[q] = bias[q*128 + w*16 + l15];

  // ---- zero both z buffers (h cols + k-pad must be 0 for MFMA) ----
  for (int i = tid; i < 2*32*(ZSTRIDE/2); i += 512) ((u32*)(&z[0][0][0]))[i] = 0;

  // x loader: 640 elems; thread covers idx {tid, tid+512}
  const int x0n = tid/20,          x0e = tid - x0n*20;
  const int x1i = tid + 512;
  const int x1n = x1i/20,          x1e = x1i - x1n*20;
  const int has1 = (x1i < 640);

  __syncthreads();
  {
    const size_t base = (size_t)nb*(TT*DD);
    z[0][x0n][x0e] = f2bf_fast(ldin(xwin, base + (size_t)x0n*(TT*DD) + x0e, isbf));
    if (has1)
      z[0][x1n][x1e] = f2bf_fast(ldin(xwin, base + (size_t)x1n*(TT*DD) + x1e, isbf));
  }

  float cst[2][4];
  #pragma unroll
  for (int mt = 0; mt < 2; mt++)
    #pragma unroll
    for (int r = 0; r < 4; r++) cst[mt][r] = 0.f;

  const f32x4 zf = {0.f, 0.f, 0.f, 0.f};
  __syncthreads();

  #pragma unroll 1
  for (int t = 0; t < TT; t++){
    const int cur = t & 1, nxt = cur ^ 1;

    // ---- prefetch x_{t+1} (global latency hidden behind MFMA/epilogue) ----
    u16 xp0 = 0, xp1 = 0;
    if (t + 1 < TT){
      const size_t base = (size_t)nb*(TT*DD) + (size_t)(t+1)*DD;
      xp0 = f2bf_fast(ldin(xwin, base + (size_t)x0n*(TT*DD) + x0e, isbf));
      if (has1)
        xp1 = f2bf_fast(ldin(xwin, base + (size_t)x1n*(TT*DD) + x1e, isbf));
    }

    // ---- A fragments from current buffer ----
    bf16x8 A[2][5];
    #pragma unroll
    for (int mt = 0; mt < 2; mt++)
      #pragma unroll
      for (int kt = 0; kt < 5; kt++)
        A[mt][kt] = *(const bf16x8*)&z[cur][mt*16 + l15][kt*32 + quad*8];

    // ---- gates GEMM: 8 independent chains of 5 MFMAs ----
    f32x4 acc[2][4];
    #pragma unroll
    for (int mt = 0; mt < 2; mt++)
      #pragma unroll
      for (int q = 0; q < 4; q++){
        f32x4 a = __builtin_amdgcn_mfma_f32_16x16x32_bf16(A[mt][0], B[q][0], zf, 0,0,0);
        a = __builtin_amdgcn_mfma_f32_16x16x32_bf16(A[mt][1], B[q][1], a, 0,0,0);
        a = __builtin_amdgcn_mfma_f32_16x16x32_bf16(A[mt][2], B[q][2], a, 0,0,0);
        a = __builtin_amdgcn_mfma_f32_16x16x32_bf16(A[mt][3], B[q][3], a, 0,0,0);
        a = __builtin_amdgcn_mfma_f32_16x16x32_bf16(A[mt][4], B[q][4], a, 0,0,0);
        acc[mt][q] = a;
      }

    // ---- epilogue: c,h update, h -> next buffer ----
    #pragma unroll
    for (int mt = 0; mt < 2; mt++)
      #pragma unroll
      for (int r = 0; r < 4; r++){
        float gi = acc[mt][0][r] + bg[0];
        float gf = acc[mt][1][r] + bg[1];
        float gg = acc[mt][2][r] + bg[2];
        float go = acc[mt][3][r] + bg[3];
        float cc = sigf(gf)*cst[mt][r] + sigf(gi)*tanhf_fast(gg);
        cst[mt][r] = cc;
        float h = sigf(go)*tanhf_fast(cc);
        const int row = mt*16 + quad*4 + r;
        z[nxt][row][DD + w*16 + l15] = f2bf_fast(h);
        if (t == TT-1)
          node_h[(size_t)(nb + row)*HH + w*16 + l15] = h;
      }

    // ---- commit x_{t+1} into next buffer ----
    if (t + 1 < TT){
      z[nxt][x0n][x0e] = xp0;
      if (has1) z[nxt][x1n][x1e] = xp1;
    }
    __syncthreads();
  }
}

// ---------------- Y[M,128] = X[M,128] @ W[128,128] (W external dtype) ------------------
__global__ __launch_bounds__(256) void gemm_kernel(const float* __restrict__ X,
    const void* __restrict__ W, const int* __restrict__ flag, float* __restrict__ Y){
  __shared__ float xs[32][128];
  const int isbf = *flag;
  const int tid = threadIdx.x;
  const int rb  = blockIdx.x*32;
  for (int idx=tid; idx<1024; idx+=256){
    int row = idx>>5, k4 = (idx&31)*4;
    *(float4*)&xs[row][k4] = *(const float4*)(X + (size_t)(rb+row)*128 + k4);
  }
  __syncthreads();
  const int col = tid & 127;
  const int r0  = (tid>>7)*16;
  float acc[16];
  #pragma unroll
  for (int r=0;r<16;r++) acc[r]=0.f;
  for (int k=0;k<128;k++){
    float w = ldin(W, (size_t)k*128 + col, isbf);
    #pragma unroll
    for (int r=0;r<16;r++) acc[r] = fmaf(w, xs[r0+r][k], acc[r]);
  }
  #pragma unroll
  for (int r=0;r<16;r++) Y[(size_t)(rb+r0+r)*128 + col] = acc[r];
}

// ---------------- per-node attention logits asr/adt [N,4] ------------------------------
__global__ __launch_bounds__(256) void att_kernel(const float* __restrict__ XH,
    const void* __restrict__ att_s, const void* __restrict__ att_d,
    const int* __restrict__ flag, float* __restrict__ asr, float* __restrict__ adt){
  __shared__ float as_[128], ad_[128];
  int isbf = *flag;
  int tid = threadIdx.x;
  if (tid < 128){ as_[tid] = ldin(att_s, tid, isbf); ad_[tid] = ldin(att_d, tid, isbf); }
  __syncthreads();
  int n = blockIdx.x*64 + (tid>>2);
  int h = tid & 3;
  if (n >= NN) return;
  const float* row = XH + (size_t)n*128 + h*32;
  float s=0.f, d=0.f;
  #pragma unroll
  for (int c=0;c<32;c++){
    float v = row[c];
    s = fmaf(v, as_[h*32+c], s);
    d = fmaf(v, ad_[h*32+c], d);
  }
  asr[n*4+h]=s; adt[n*4+h]=d;
}

// ---------------- edge softmax (3 passes, atomics) --------------------------------------
__device__ __forceinline__ u32 fkey(float x){
  u32 b = __float_as_uint(x);
  return (b & 0x80000000u) ? ~b : (b | 0x80000000u);
}
__device__ __forceinline__ float unkey(u32 k){
  return (k & 0x80000000u) ? __uint_as_float(k ^ 0x80000000u) : __uint_as_float(~k);
}
__device__ __forceinline__ void edge_sd(int e, const int* src, const int* dst, int& s, int& d){
  if (e < EE){ s = src[e]; d = dst[e]; } else { s = e - EE; d = s; }
}

__global__ void edge_max_kernel(const int* __restrict__ src, const int* __restrict__ dst,
    const float* __restrict__ asr, const float* __restrict__ adt, u32* __restrict__ emax){
  int e = blockIdx.x*256 + threadIdx.x;
  if (e >= EA) return;
  int s,d; edge_sd(e, src, dst, s, d);
  float4 a = *(const float4*)(asr + (size_t)s*4);
  float4 b = *(const float4*)(adt + (size_t)d*4);
  float v[4] = {a.x+b.x, a.y+b.y, a.z+b.z, a.w+b.w};
  #pragma unroll
  for (int h=0;h<4;h++){
    float x = v[h] > 0.f ? v[h] : 0.2f*v[h];
    atomicMax(emax + (size_t)d*4 + h, fkey(x));
  }
}

__global__ void edge_exp_kernel(const int* __restrict__ src, const int* __restrict__ dst,
    const float* __restrict__ asr, const float* __restrict__ adt,
    const u32* __restrict__ emax, float* __restrict__ exb, float* __restrict__ den){
  int e = blockIdx.x*256 + threadIdx.x;
  if (e >= EA) return;
  int s,d; edge_sd(e, src, dst, s, d);
  float4 a = *(const float4*)(asr + (size_t)s*4);
  float4 b = *(const float4*)(adt + (size_t)d*4);
  float v[4] = {a.x+b.x, a.y+b.y, a.z+b.z, a.w+b.w};
  uint4 mk = *(const uint4*)(emax + (size_t)d*4);
  u32 mka[4] = {mk.x, mk.y, mk.z, mk.w};
  float4 exv;
  float* exp_ = &exv.x;
  #pragma unroll
  for (int h=0;h<4;h++){
    float x = v[h] > 0.f ? v[h] : 0.2f*v[h];
    float ex = __expf(x - unkey(mka[h]));
    exp_[h] = ex;
    atomicAdd(den + (size_t)d*4 + h, ex);
  }
  *(float4*)(exb + (size_t)e*4) = exv;
}

// unnormalized aggregate: agg[d] += ex * XH[s]  (den division hoisted to elu_kernel)
__global__ __launch_bounds__(256) void edge_agg_kernel(const int* __restrict__ src,
    const int* __restrict__ dst, const float* __restrict__ exb,
    const float* __restrict__ XH, float* __restrict__ agg){
  int eg = blockIdx.x*2 + (threadIdx.x>>7);
  int c  = threadIdx.x & 127;
  if (eg >= EA) return;
  int s,d; edge_sd(eg, src, dst, s, d);
  int h = c>>5;
  float wgt = exb[(size_t)eg*4 + h];
  atomicAdd(agg + (size_t)d*128 + c, wgt * XH[(size_t)s*128 + c]);
}

// ---------------- epilogues -------------------------------------------------------------
// buf = (unnormalized agg)/den + bias, then ELU
__global__ void elu_kernel(float* __restrict__ buf, const void* __restrict__ bias,
                           const float* __restrict__ den, const int* __restrict__ flag){
  int isbf = *flag;
  int idx = blockIdx.x*256 + threadIdx.x;
  if (idx >= NN*128) return;
  int n = idx >> 7, c = idx & 127, h = c >> 5;
  float v = buf[idx]*__builtin_amdgcn_rcpf(den[(size_t)n*4 + h]) + ldin(bias, c, isbf);
  buf[idx] = v > 0.f ? v : __expf(v) - 1.f;   // den >= 1 (self-loop at max), rcp safe
}

__global__ void head_kernel(const float* __restrict__ Hf, const void* __restrict__ Wh,
    const void* __restrict__ bh, const int* __restrict__ flag, void* __restrict__ out){
  int isbf = *flag;
  int n = blockIdx.x*256 + threadIdx.x;
  if (n >= NN) return;
  float a0 = ldin(bh, 0, isbf), a1 = ldin(bh, 1, isbf);
  const float* row = Hf + (size_t)n*128;
  #pragma unroll 4
  for (int k=0;k<128;k++){
    float v = row[k];
    a0 = fmaf(v, ldin(Wh, (size_t)k*2,   isbf), a0);
    a1 = fmaf(v, ldin(Wh, (size_t)k*2+1, isbf), a1);
  }
  if (isbf){
    u16* o = (u16*)out;
    o[n*2]   = f2bf_fast(a0);
    o[n*2+1] = f2bf_fast(a1);
  } else {
    float* o = (float*)out;
    o[n*2]   = a0;
    o[n*2+1] = a1;
  }
}

// ---------------- launch ----------------------------------------------------------------
extern "C" void kernel_launch(void* const* d_in, const int* in_sizes, int n_in,
                              void* d_out, int out_size, void* d_ws, size_t ws_size,
                              hipStream_t stream){
  const void* xwin = d_in[0];
  const int* eidx  = (const int*)d_in[1];
  const void* Wih  = d_in[2];
  const void* Whh  = d_in[3];
  const void* bih  = d_in[4];
  const void* bhh  = d_in[5];
  const void* W1   = d_in[6];
  const void* as1  = d_in[7];
  const void* ad1  = d_in[8];
  const void* b1   = d_in[9];
  const void* W2   = d_in[10];
  const void* as2  = d_in[11];
  const void* ad2  = d_in[12];
  const void* b2   = d_in[13];
  const void* Wh   = d_in[14];
  const void* bh   = d_in[15];
  const int* src = eidx;
  const int* dst = eidx + EE;

  char* ws = (char*)d_ws;
  size_t off = 0;
  auto alloc = [&](size_t bytes)->void*{
    void* p = ws + off; off += (bytes + 255) & ~(size_t)255; return p;
  };
  u16*   Wfrag = (u16*) alloc((size_t)8*4*5*64*8*sizeof(u16));
  float* bias  = (float*)alloc(512*sizeof(float));
  float* bufA  = (float*)alloc((size_t)NN*128*sizeof(float));  // node_h -> agg2/h2
  float* bufB  = (float*)alloc((size_t)NN*128*sizeof(float));  // xh1 -> xh2
  float* bufC  = (float*)alloc((size_t)NN*128*sizeof(float));  // agg1/h1
  float* asr   = (float*)alloc((size_t)NN*4*sizeof(float));
  float* adt   = (float*)alloc((size_t)NN*4*sizeof(float));
  u32*   emax  = (u32*)  alloc((size_t)NN*4*sizeof(u32));
  float* den   = (float*)alloc((size_t)NN*4*sizeof(float));
  float* exb   = (float*)alloc((size_t)EA*4*sizeof(float));
  int*   flag  = (int*)  alloc(sizeof(int));
  (void)ws_size; (void)in_sizes; (void)n_in; (void)out_size;

  detect_kernel<<<1, 256, 0, stream>>>((const u16*)xwin, flag);
  prep_kernel<<<(8*4*5*64*8+255)/256, 256, 0, stream>>>(Wih, Whh, bih, bhh, flag, Wfrag, bias);
  lstm_kernel<<<NN/32, 512, 0, stream>>>(xwin, Wfrag, bias, flag, bufA);

  const int EGRID = (EA+255)/256;
  // ---- GAT layer 1 ----
  gemm_kernel<<<NN/32, 256, 0, stream>>>(bufA, W1, flag, bufB);
  att_kernel<<<(NN+63)/64, 256, 0, stream>>>(bufB, as1, ad1, flag, asr, adt);
  hipMemsetAsync(emax, 0, (size_t)NN*4*sizeof(u32), stream);
  hipMemsetAsync(den,  0, (size_t)NN*4*sizeof(float), stream);
  edge_max_kernel<<<EGRID, 256, 0, stream>>>(src, dst, asr, adt, emax);
  edge_exp_kernel<<<EGRID, 256, 0, stream>>>(src, dst, asr, adt, emax, exb, den);
  hipMemsetAsync(bufC, 0, (size_t)NN*128*sizeof(float), stream);
  edge_agg_kernel<<<EA/2, 256, 0, stream>>>(src, dst, exb, bufB, bufC);
  elu_kernel<<<(NN*128+255)/256, 256, 0, stream>>>(bufC, b1, den, flag);
  // ---- GAT layer 2 ----
  gemm_kernel<<<NN/32, 256, 0, stream>>>(bufC, W2, flag, bufB);
  att_kernel<<<(NN+63)/64, 256, 0, stream>>>(bufB, as2, ad2, flag, asr, adt);
  hipMemsetAsync(emax, 0, (size_t)NN*4*sizeof(u32), stream);
  hipMemsetAsync(den,  0, (size_t)NN*4*sizeof(float), stream);
  edge_max_kernel<<<EGRID, 256, 0, stream>>>(src, dst, asr, adt, emax);
  edge_exp_kernel<<<EGRID, 256, 0, stream>>>(src, dst, asr, adt, emax, exb, den);
  hipMemsetAsync(bufA, 0, (size_t)NN*128*sizeof(float), stream);
  edge_agg_kernel<<<EA/2, 256, 0, stream>>>(src, dst, exb, bufB, bufA);
  elu_kernel<<<(NN*128+255)/256, 256, 0, stream>>>(bufA, b2, den, flag);
  // ---- head ----
  head_kernel<<<(NN+255)/256, 256, 0, stream>>>(bufA, Wh, bh, flag, d_out);
}

// Round 5
// 818.465 us; speedup vs baseline: 7.3175x; 1.5493x over previous
//
#include <hip/hip_runtime.h>
#include <hip/hip_bf16.h>

#define NN 20000
#define TT 60
#define DD 20
#define HH 128
#define KK 148      // DD + HH
#define EE 320000
#define EA 340000   // EE + NN (self loops)
#define ZSTRIDE 168 // z row stride in u16 (mult of 8 -> b128-aligned rows)

typedef unsigned short u16;
typedef unsigned int u32;
typedef __attribute__((ext_vector_type(8))) short bf16x8;  // 8 bf16 = 4 VGPRs
typedef __attribute__((ext_vector_type(4))) float f32x4;

__device__ __forceinline__ float bf2f(u16 u){ return __uint_as_float(((u32)u)<<16); }
__device__ __forceinline__ u16 f2bf(float f){   // RNE, values bounded (no NaN inputs)
  u32 x = __float_as_uint(f);
  return (u16)((x + 0x7FFFu + ((x >> 16) & 1u)) >> 16);
}
__device__ __forceinline__ float sigf(float x){
  return __builtin_amdgcn_rcpf(1.f + __expf(-x));
}
__device__ __forceinline__ float tanhf_fast(float x){
  return 1.f - 2.f*__builtin_amdgcn_rcpf(1.f + __expf(2.f*x));
}

// ---------------- prep: LSTM Wfrag (fused [Wih|Whh], MFMA B-layout) + bias --------------
// Wfrag[((w*20 + q*5 + kt)*64 + lane)*8 + j]; col=q*128+w*16+(lane&15); k=kt*32+(lane>>4)*8+j
__global__ void prep_lstm_kernel(const float* __restrict__ Wih, const float* __restrict__ Whh,
                                 const float* __restrict__ bih, const float* __restrict__ bhh,
                                 u16* __restrict__ Wfrag, float* __restrict__ bias){
  int idx = blockIdx.x*256 + threadIdx.x;
  if (idx < 8*4*5*64*8){
    int j    = idx & 7;
    int lane = (idx >> 3) & 63;
    int rest = idx >> 9;           // w*20 + q*5 + kt
    int kt = rest % 5, q = (rest/5) & 3, w = rest/20;
    int col = q*128 + w*16 + (lane & 15);
    int k   = kt*32 + ((lane >> 4) & 3)*8 + j;
    float v = 0.f;
    if (k < DD)       v = Wih[(size_t)col*DD + k];
    else if (k < KK)  v = Whh[(size_t)col*HH + (k - DD)];
    Wfrag[idx] = f2bf(v);
  }
  if (idx < 512) bias[idx] = bih[idx] + bhh[idx];
}

// ---------------- prep: GAT weight W[128][128] fp32 -> MFMA B-frag bf16 -----------------
// Wf[((ct*4 + kt)*64 + lane)*8 + j]: col=ct*16+(lane&15), k=kt*32+(lane>>4)*8+j
__global__ void prep_w_kernel(const float* __restrict__ W, u16* __restrict__ Wf){
  int idx = blockIdx.x*256 + threadIdx.x;
  if (idx >= 8*4*64*8) return;
  int j = idx & 7, lane = (idx>>3) & 63, kt = (idx>>9) & 3, ct = idx>>11;
  int col = ct*16 + (lane & 15);
  int k   = kt*32 + ((lane>>4) & 3)*8 + j;
  Wf[idx] = f2bf(W[(size_t)k*128 + col]);
}

// ---------------- LSTM: MFMA recurrence, 64 nodes/block, 8 waves x 16 channels ----------
__global__ __launch_bounds__(512) void lstm_kernel(const float* __restrict__ xwin,
    const u16* __restrict__ Wfrag, const float* __restrict__ bias,
    u16* __restrict__ node_h){
  __shared__ u16 z[2][64][ZSTRIDE];   // [buf][node][ x(0..19) | h(20..147) | pad0 ]
  const int tid  = threadIdx.x;
  const int lane = tid & 63;
  const int w    = tid >> 6;
  const int nb   = blockIdx.x * 64;
  const int l15  = lane & 15;
  const int quad = lane >> 4;

  // ---- B fragments: 20 x bf16x8 = 80 regs, persistent across 60 steps ----
  bf16x8 B[4][5];
  {
    const bf16x8* bp = (const bf16x8*)Wfrag;
    #pragma unroll
    for (int q = 0; q < 4; q++)
      #pragma unroll
      for (int kt = 0; kt < 5; kt++)
        B[q][kt] = bp[(size_t)((w*20 + q*5 + kt)*64 + lane)];
  }
  float bg[4];
  #pragma unroll
  for (int q = 0; q < 4; q++) bg[q] = bias[q*128 + w*16 + l15];

  // ---- zero both z buffers ----
  for (int i = tid; i < 2*64*(ZSTRIDE/2); i += 512) ((u32*)(&z[0][0][0]))[i] = 0;

  // x loaders: 1280 elems; thread covers {tid, tid+512, tid+1024}
  const int n0 = tid/20,        e0 = tid - n0*20;
  const int i1 = tid + 512;
  const int n1 = i1/20,         e1 = i1 - n1*20;
  const int i2 = tid + 1024;
  const int n2 = i2/20,         e2 = i2 - n2*20;
  const int has2 = (i2 < 1280);
  const float* p0 = xwin + (size_t)min(nb+n0, NN-1)*(TT*DD) + e0;
  const float* p1 = xwin + (size_t)min(nb+n1, NN-1)*(TT*DD) + e1;
  const float* p2 = xwin + (size_t)min(nb+n2, NN-1)*(TT*DD) + e2;

  __syncthreads();
  z[0][n0][e0] = f2bf(p0[0]);
  z[0][n1][e1] = f2bf(p1[0]);
  if (has2) z[0][n2][e2] = f2bf(p2[0]);

  f32x4 cst[4];                          // c-state [g*2+mt2]
  const f32x4 zf = {0.f, 0.f, 0.f, 0.f};
  #pragma unroll
  for (int i = 0; i < 4; i++) cst[i] = zf;
  __syncthreads();

  #pragma unroll 1
  for (int t = 0; t < TT; t++){
    const int cur = t & 1, nxt = cur ^ 1;

    float xf0 = 0.f, xf1 = 0.f, xf2 = 0.f;
    if (t + 1 < TT){
      xf0 = p0[(t+1)*DD];
      xf1 = p1[(t+1)*DD];
      if (has2) xf2 = p2[(t+1)*DD];
    }

    // ---- two node-tile groups of 32 (A/acc registers reused) ----
    #pragma unroll
    for (int g = 0; g < 2; g++){
      bf16x8 A[2][5];
      #pragma unroll
      for (int mt = 0; mt < 2; mt++)
        #pragma unroll
        for (int kt = 0; kt < 5; kt++)
          A[mt][kt] = *(const bf16x8*)&z[cur][g*32 + mt*16 + l15][kt*32 + quad*8];

      f32x4 acc[2][4];
      #pragma unroll
      for (int mt = 0; mt < 2; mt++)
        #pragma unroll
        for (int q = 0; q < 4; q++){
          f32x4 a = __builtin_amdgcn_mfma_f32_16x16x32_bf16(A[mt][0], B[q][0], zf, 0,0,0);
          a = __builtin_amdgcn_mfma_f32_16x16x32_bf16(A[mt][1], B[q][1], a, 0,0,0);
          a = __builtin_amdgcn_mfma_f32_16x16x32_bf16(A[mt][2], B[q][2], a, 0,0,0);
          a = __builtin_amdgcn_mfma_f32_16x16x32_bf16(A[mt][3], B[q][3], a, 0,0,0);
          a = __builtin_amdgcn_mfma_f32_16x16x32_bf16(A[mt][4], B[q][4], a, 0,0,0);
          acc[mt][q] = a;
        }

      #pragma unroll
      for (int mt = 0; mt < 2; mt++){
        f32x4 cv = cst[g*2 + mt];
        #pragma unroll
        for (int r = 0; r < 4; r++){
          float gi = acc[mt][0][r] + bg[0];
          float gf = acc[mt][1][r] + bg[1];
          float gg = acc[mt][2][r] + bg[2];
          float go = acc[mt][3][r] + bg[3];
          float cc = sigf(gf)*cv[r] + sigf(gi)*tanhf_fast(gg);
          cv[r] = cc;
          float h = sigf(go)*tanhf_fast(cc);
          const int row = g*32 + mt*16 + quad*4 + r;
          u16 hb = f2bf(h);
          z[nxt][row][DD + w*16 + l15] = hb;
          if (t == TT-1 && nb + row < NN)
            node_h[(size_t)(nb + row)*HH + w*16 + l15] = hb;
        }
        cst[g*2 + mt] = cv;
      }
    }

    if (t + 1 < TT){
      z[nxt][n0][e0] = f2bf(xf0);
      z[nxt][n1][e1] = f2bf(xf1);
      if (has2) z[nxt][n2][e2] = f2bf(xf2);
    }
    __syncthreads();
  }
}

// ---------------- MFMA GEMM: Y[M,128] f32 = X[M,128] bf16 @ Wf (B-frags) ----------------
__global__ __launch_bounds__(256) void gemm_kernel(const u16* __restrict__ X,
    const u16* __restrict__ Wf, float* __restrict__ Y){
  __shared__ u16 xs[32][136];           // +8 pad
  const int tid = threadIdx.x, lane = tid & 63, w = tid >> 6;
  const int l15 = lane & 15, quad = lane >> 4;
  const int rb  = blockIdx.x*32;

  for (int c = tid; c < 512; c += 256){
    int row = c >> 4, cc = c & 15;
    *(bf16x8*)&xs[row][cc*8] = *(const bf16x8*)&X[(size_t)(rb+row)*128 + cc*8];
  }
  bf16x8 Bf[2][4];
  #pragma unroll
  for (int ct = 0; ct < 2; ct++)
    #pragma unroll
    for (int kt = 0; kt < 4; kt++)
      Bf[ct][kt] = *(const bf16x8*)&Wf[(size_t)((((2*w+ct)*4 + kt)*64 + lane))*8];
  __syncthreads();

  bf16x8 A[2][4];
  #pragma unroll
  for (int mt = 0; mt < 2; mt++)
    #pragma unroll
    for (int kt = 0; kt < 4; kt++)
      A[mt][kt] = *(const bf16x8*)&xs[mt*16 + l15][kt*32 + quad*8];

  const f32x4 zf = {0.f,0.f,0.f,0.f};
  #pragma unroll
  for (int mt = 0; mt < 2; mt++)
    #pragma unroll
    for (int ct = 0; ct < 2; ct++){
      f32x4 a = __builtin_amdgcn_mfma_f32_16x16x32_bf16(A[mt][0], Bf[ct][0], zf, 0,0,0);
      a = __builtin_amdgcn_mfma_f32_16x16x32_bf16(A[mt][1], Bf[ct][1], a, 0,0,0);
      a = __builtin_amdgcn_mfma_f32_16x16x32_bf16(A[mt][2], Bf[ct][2], a, 0,0,0);
      a = __builtin_amdgcn_mfma_f32_16x16x32_bf16(A[mt][3], Bf[ct][3], a, 0,0,0);
      #pragma unroll
      for (int r = 0; r < 4; r++)
        Y[(size_t)(rb + mt*16 + quad*4 + r)*128 + (2*w+ct)*16 + l15] = a[r];
    }
}

// ---------------- per-node attention logits asr/adt [N,4] -------------------------------
__global__ __launch_bounds__(256) void att_kernel(const float* __restrict__ XH,
    const float* __restrict__ att_s, const float* __restrict__ att_d,
    float* __restrict__ asr, float* __restrict__ adt){
  __shared__ float as_[128], ad_[128];
  int tid = threadIdx.x;
  if (tid < 128){ as_[tid] = att_s[tid]; ad_[tid] = att_d[tid]; }
  __syncthreads();
  int n = blockIdx.x*64 + (tid>>2);
  int h = tid & 3;
  if (n >= NN) return;
  const float* row = XH + (size_t)n*128 + h*32;
  float s = 0.f, d = 0.f;
  #pragma unroll
  for (int c = 0; c < 32; c++){
    float v = row[c];
    s = fmaf(v, as_[h*32+c], s);
    d = fmaf(v, ad_[h*32+c], d);
  }
  asr[n*4+h] = s; adt[n*4+h] = d;
}

// ---------------- CSR build -------------------------------------------------------------
__device__ __forceinline__ void edge_sd(int e, const int* src, const int* dst, int& s, int& d){
  if (e < EE){ s = src[e]; d = dst[e]; } else { s = e - EE; d = s; }
}

__global__ void deg_kernel(const int* __restrict__ src, const int* __restrict__ dst,
                           int* __restrict__ deg){
  int e = blockIdx.x*256 + threadIdx.x;
  if (e >= EA) return;
  int s, d; edge_sd(e, src, dst, s, d);
  atomicAdd(deg + d, 1);
}

__global__ __launch_bounds__(1024) void scan_kernel(const int* __restrict__ deg,
    int* __restrict__ rowptr, int* __restrict__ cursor){
  __shared__ int buf[1024];
  __shared__ int carry_s;
  const int tid = threadIdx.x;
  if (tid == 0) carry_s = 0;
  __syncthreads();
  for (int base = 0; base < NN; base += 1024){
    int idx = base + tid;
    int v = (idx < NN) ? deg[idx] : 0;
    buf[tid] = v;
    __syncthreads();
    #pragma unroll
    for (int off = 1; off < 1024; off <<= 1){
      int t = (tid >= off) ? buf[tid - off] : 0;
      __syncthreads();
      buf[tid] += t;
      __syncthreads();
    }
    int excl = buf[tid] - v;
    int c = carry_s;
    if (idx < NN){ rowptr[idx] = c + excl; cursor[idx] = c + excl; }
    int total = buf[1023];
    __syncthreads();
    if (tid == 0) carry_s = c + total;
    __syncthreads();
  }
  if (tid == 0) rowptr[NN] = carry_s;   // == EA
}

__global__ void fill_kernel(const int* __restrict__ src, const int* __restrict__ dst,
                            int* __restrict__ cursor, int* __restrict__ elist){
  int e = blockIdx.x*256 + threadIdx.x;
  if (e >= EA) return;
  int s, d; edge_sd(e, src, dst, s, d);
  int pos = atomicAdd(cursor + d, 1);
  elist[pos] = s;
}

// ---------------- fused GAT: per-dst softmax + aggregate + bias + ELU -> bf16 -----------
__global__ __launch_bounds__(512) void gat_kernel(const int* __restrict__ rowptr,
    const int* __restrict__ elist, const float* __restrict__ asr,
    const float* __restrict__ adt, const float* __restrict__ XH,
    const float* __restrict__ bias, u16* __restrict__ out){
  const int tid = threadIdx.x, lane = tid & 63, w = tid >> 6;
  const int d = blockIdx.x*8 + w;            // NN % 8 == 0
  const int r0 = rowptr[d], r1 = rowptr[d+1];
  const int h = lane >> 4;
  float4 ad4 = *(const float4*)(adt + (size_t)d*4);

  // pass 1: per-head max
  float m0=-1e30f, m1=-1e30f, m2=-1e30f, m3=-1e30f;
  for (int base = r0; base < r1; base += 64){
    int idx = base + lane;
    float l0=-1e30f, l1=-1e30f, l2=-1e30f, l3=-1e30f;
    if (idx < r1){
      int s = elist[idx];
      float4 a = *(const float4*)(asr + (size_t)s*4);
      l0 = a.x + ad4.x; l0 = l0 > 0.f ? l0 : 0.2f*l0;
      l1 = a.y + ad4.y; l1 = l1 > 0.f ? l1 : 0.2f*l1;
      l2 = a.z + ad4.z; l2 = l2 > 0.f ? l2 : 0.2f*l2;
      l3 = a.w + ad4.w; l3 = l3 > 0.f ? l3 : 0.2f*l3;
    }
    m0 = fmaxf(m0, l0); m1 = fmaxf(m1, l1); m2 = fmaxf(m2, l2); m3 = fmaxf(m3, l3);
  }
  #pragma unroll
  for (int off = 32; off > 0; off >>= 1){
    m0 = fmaxf(m0, __shfl_xor(m0, off));
    m1 = fmaxf(m1, __shfl_xor(m1, off));
    m2 = fmaxf(m2, __shfl_xor(m2, off));
    m3 = fmaxf(m3, __shfl_xor(m3, off));
  }
  // pass 2: per-head denom
  float s0=0.f, s1=0.f, s2=0.f, s3=0.f;
  for (int base = r0; base < r1; base += 64){
    int idx = base + lane;
    if (idx < r1){
      int s = elist[idx];
      float4 a = *(const float4*)(asr + (size_t)s*4);
      float l0 = a.x + ad4.x; l0 = l0 > 0.f ? l0 : 0.2f*l0;
      float l1 = a.y + ad4.y; l1 = l1 > 0.f ? l1 : 0.2f*l1;
      float l2 = a.z + ad4.z; l2 = l2 > 0.f ? l2 : 0.2f*l2;
      float l3 = a.w + ad4.w; l3 = l3 > 0.f ? l3 : 0.2f*l3;
      s0 += __expf(l0 - m0); s1 += __expf(l1 - m1);
      s2 += __expf(l2 - m2); s3 += __expf(l3 - m3);
    }
  }
  #pragma unroll
  for (int off = 32; off > 0; off >>= 1){
    s0 += __shfl_xor(s0, off); s1 += __shfl_xor(s1, off);
    s2 += __shfl_xor(s2, off); s3 += __shfl_xor(s3, off);
  }
  const float mh  = (h==0) ? m0 : (h==1) ? m1 : (h==2) ? m2 : m3;
  const float adh = (h==0) ? ad4.x : (h==1) ? ad4.y : (h==2) ? ad4.z : ad4.w;
  const float rdh = __builtin_amdgcn_rcpf((h==0) ? s0 : (h==1) ? s1 : (h==2) ? s2 : s3);

  // pass 3: weighted gather (sequential over edges, all lanes)
  const int c = lane*2;
  float accx = 0.f, accy = 0.f;
  for (int idx = r0; idx < r1; idx++){
    int s = elist[idx];
    float4 a = *(const float4*)(asr + (size_t)s*4);
    float av = (h==0) ? a.x : (h==1) ? a.y : (h==2) ? a.z : a.w;
    float l = av + adh; l = l > 0.f ? l : 0.2f*l;
    float wt = __expf(l - mh) * rdh;
    float2 xy = *(const float2*)(XH + (size_t)s*128 + c);
    accx = fmaf(wt, xy.x, accx);
    accy = fmaf(wt, xy.y, accy);
  }
  float vx = accx + bias[c], vy = accy + bias[c+1];
  vx = vx > 0.f ? vx : __expf(vx) - 1.f;
  vy = vy > 0.f ? vy : __expf(vy) - 1.f;
  u32 pk = (u32)f2bf(vx) | ((u32)f2bf(vy) << 16);
  ((u32*)out)[(size_t)d*64 + lane] = pk;
}

// ---------------- head ------------------------------------------------------------------
__global__ void head_kernel(const u16* __restrict__ Hf, const float* __restrict__ Wh,
    const float* __restrict__ bh, float* __restrict__ out){
  int n = blockIdx.x*256 + threadIdx.x;
  if (n >= NN) return;
  float a0 = bh[0], a1 = bh[1];
  const u16* row = Hf + (size_t)n*128;
  #pragma unroll 4
  for (int k = 0; k < 128; k++){
    float v = bf2f(row[k]);
    a0 = fmaf(v, Wh[k*2],   a0);
    a1 = fmaf(v, Wh[k*2+1], a1);
  }
  float2 o; o.x = a0; o.y = a1;
  ((float2*)out)[n] = o;
}

// ---------------- launch ----------------------------------------------------------------
extern "C" void kernel_launch(void* const* d_in, const int* in_sizes, int n_in,
                              void* d_out, int out_size, void* d_ws, size_t ws_size,
                              hipStream_t stream){
  const float* xwin = (const float*)d_in[0];
  const int*   eidx = (const int*)d_in[1];
  const float* Wih  = (const float*)d_in[2];
  const float* Whh  = (const float*)d_in[3];
  const float* bih  = (const float*)d_in[4];
  const float* bhh  = (const float*)d_in[5];
  const float* W1   = (const float*)d_in[6];
  const float* as1  = (const float*)d_in[7];
  const float* ad1  = (const float*)d_in[8];
  const float* b1   = (const float*)d_in[9];
  const float* W2   = (const float*)d_in[10];
  const float* as2  = (const float*)d_in[11];
  const float* ad2  = (const float*)d_in[12];
  const float* b2   = (const float*)d_in[13];
  const float* Wh   = (const float*)d_in[14];
  const float* bh   = (const float*)d_in[15];
  const int* src = eidx;
  const int* dst = eidx + EE;

  char* ws = (char*)d_ws;
  size_t off = 0;
  auto alloc = [&](size_t bytes)->void*{
    void* p = ws + off; off += (bytes + 255) & ~(size_t)255; return p;
  };
  u16*   WfL   = (u16*)  alloc((size_t)8*4*5*64*8*sizeof(u16));
  u16*   W1f   = (u16*)  alloc((size_t)8*4*64*8*sizeof(u16));
  u16*   W2f   = (u16*)  alloc((size_t)8*4*64*8*sizeof(u16));
  float* bias  = (float*)alloc(512*sizeof(float));
  u16*   nodeh = (u16*)  alloc((size_t)NN*128*sizeof(u16));
  float* xh    = (float*)alloc((size_t)NN*128*sizeof(float));
  u16*   hbuf  = (u16*)  alloc((size_t)NN*128*sizeof(u16));
  float* asr   = (float*)alloc((size_t)NN*4*sizeof(float));
  float* adt   = (float*)alloc((size_t)NN*4*sizeof(float));
  int*   deg   = (int*)  alloc((size_t)NN*sizeof(int));
  int*   rowp  = (int*)  alloc((size_t)(NN+1)*sizeof(int));
  int*   curs  = (int*)  alloc((size_t)NN*sizeof(int));
  int*   elist = (int*)  alloc((size_t)EA*sizeof(int));
  (void)ws_size; (void)in_sizes; (void)n_in; (void)out_size;

  const int EGRID = (EA+255)/256;

  // weight prep + CSR build
  prep_lstm_kernel<<<(8*4*5*64*8+255)/256, 256, 0, stream>>>(Wih, Whh, bih, bhh, WfL, bias);
  prep_w_kernel<<<(8*4*64*8+255)/256, 256, 0, stream>>>(W1, W1f);
  prep_w_kernel<<<(8*4*64*8+255)/256, 256, 0, stream>>>(W2, W2f);
  hipMemsetAsync(deg, 0, (size_t)NN*sizeof(int), stream);
  deg_kernel<<<EGRID, 256, 0, stream>>>(src, dst, deg);
  scan_kernel<<<1, 1024, 0, stream>>>(deg, rowp, curs);
  fill_kernel<<<EGRID, 256, 0, stream>>>(src, dst, curs, elist);

  // LSTM
  lstm_kernel<<<(NN+63)/64, 512, 0, stream>>>(xwin, WfL, bias, nodeh);

  // GAT layer 1
  gemm_kernel<<<NN/32, 256, 0, stream>>>(nodeh, W1f, xh);
  att_kernel<<<(NN+63)/64, 256, 0, stream>>>(xh, as1, ad1, asr, adt);
  gat_kernel<<<NN/8, 512, 0, stream>>>(rowp, elist, asr, adt, xh, b1, hbuf);
  // GAT layer 2
  gemm_kernel<<<NN/32, 256, 0, stream>>>(hbuf, W2f, xh);
  att_kernel<<<(NN+63)/64, 256, 0, stream>>>(xh, as2, ad2, asr, adt);
  gat_kernel<<<NN/8, 512, 0, stream>>>(rowp, elist, asr, adt, xh, b2, hbuf);
  // head
  head_kernel<<<(NN+255)/256, 256, 0, stream>>>(hbuf, Wh, bh, (float*)d_out);
}